// Round 3
// baseline (352.880 us; speedup 1.0000x reference)
//
#include <hip/hip_runtime.h>
#include <cstdint>

// ---------------------------------------------------------------------------
// RegionModel R17: conv1 software pipeline; conv2/conv3 reverted to R14.
// R15/R16 lessons: (a) not HBM-bound (poison fill = 6.9 TB/s writes);
// (b) raising blocks/CU on conv2/conv3 REGRESSED (-21us) -> wave count is
// not the lever; every wave parks at the same stage barrier.
// R17: conv1 block owns 8 row-groups (grid 2x4xC = 1024 blocks, 4/CU) with
// a 2-deep issue-early/use-late pipeline + double-buffered LDS tile:
//   iter t: issue loads(t+2) ; MFMA+store(t, buf) ; convert(t+1 -> buf^1) ;
//           __syncthreads()
// Loads get a full compute phase between issue and first use, so the
// barrier's vmcnt drain lands on ~1.5K-cycle-old loads. conv2/conv3 = R14.
// ---------------------------------------------------------------------------

typedef __attribute__((ext_vector_type(8))) short short8;
typedef __attribute__((ext_vector_type(4))) float floatx4;
typedef __attribute__((ext_vector_type(4))) unsigned short ushort4v;
typedef __attribute__((ext_vector_type(4))) float float4v;

__device__ inline unsigned short f2bf(float f) {
  union { float f; unsigned u; } x;
  x.f = f;
  unsigned u = x.u;
  u += 0x7FFFu + ((u >> 16) & 1u);  // round-to-nearest-even
  return (unsigned short)(u >> 16);
}

// Async 16B global->LDS DMA. LDS dest = wave-uniform base + lane*16.
__device__ inline void g2l16(const unsigned short* g, unsigned short* l) {
  __builtin_amdgcn_global_load_lds(
      (const __attribute__((address_space(1))) unsigned int*)g,
      (__attribute__((address_space(3))) unsigned int*)(unsigned int)(uintptr_t)l,
      16, 0, 0);
}

__global__ __launch_bounds__(128) void prep_k(const int* __restrict__ rp,
                                              int* __restrict__ rout,
                                              float* __restrict__ feat) {
  __shared__ int is64;
  if (threadIdx.x == 0) {
    int odd_or = 0;
    for (int i = 0; i < 64; ++i) odd_or |= rp[2 * i + 1];
    is64 = (odd_or == 0) ? 1 : 0;
  }
  __syncthreads();
  int b = threadIdx.x;
  int r = is64 ? rp[2 * b] : rp[b];
  rout[b] = r & 7;
  float* fr = feat + b * 128;
  for (int j = 0; j < 128; ++j) fr[j] = 0.f;
}

// conv1 weights -> [r][kg(2)][mt(2)][lane][j] ; k = kg*32+q*8+j maps to
// row = kg*2+(q>>1), idx=(q&1)*8+j, kx=idx>>2, c=idx&3; pad slots -> 0.
__global__ __launch_bounds__(256) void pack1_k(const float* __restrict__ w,
                                               unsigned short* __restrict__ dst) {
  int t = blockIdx.x * blockDim.x + threadIdx.x;
  if (t >= 16384) return;
  int j = t & 7, lane = (t >> 3) & 63, mt = (t >> 9) & 1, kg = (t >> 10) & 1,
      r = t >> 11;
  int oc = mt * 16 + (lane & 15);
  int q = (lane >> 4) & 3;
  int row = kg * 2 + (q >> 1);
  int idx = (q & 1) * 8 + j;
  int kx = idx >> 2, c = idx & 3;
  float val = 0.f;
  if (row < 3 && kx < 3 && c < 3) val = w[((r * 32 + oc) * 3 + c) * 9 + row * 3 + kx];
  dst[t] = f2bf(val);
}

// conv2/3 weights [R][OC][IC][3][3] -> [r][tap][s][mt][lane][j], ic=s*32+q*8+j
template <int OC, int IC, int SUBK, int MTG>
__global__ __launch_bounds__(256) void packT_k(const float* __restrict__ w,
                                               unsigned short* __restrict__ dst) {
  const int total = 8 * 9 * SUBK * MTG * 512;
  int t = blockIdx.x * blockDim.x + threadIdx.x;
  if (t >= total) return;
  int j = t & 7, lane = (t >> 3) & 63;
  int u = t >> 9;
  int mt = u % MTG; u /= MTG;
  int s = u % SUBK; u /= SUBK;
  int tap = u % 9;
  int r = u / 9;
  int oc = mt * 16 + (lane & 15);
  int ic = s * 32 + ((lane >> 4) & 3) * 8 + j;
  dst[t] = f2bf(w[((r * OC + oc) * IC + ic) * 9 + tap]);
}

// zero halo of channel-group plane buffer [nplane][HP][WP][8]
__global__ __launch_bounds__(256) void halo8_k(unsigned short* __restrict__ buf,
                                               int nplane, int HP, int WP) {
  int per = 2 * WP + 2 * (HP - 2);
  int t = blockIdx.x * blockDim.x + threadIdx.x;
  if (t >= nplane * per) return;
  int s = t / per, i = t - s * per;
  int y, x;
  if (i < WP) { y = 0; x = i; }
  else if (i < 2 * WP) { y = HP - 1; x = i - WP; }
  else {
    int ii = i - 2 * WP;
    y = 1 + (ii >> 1);
    x = (ii & 1) ? (WP - 1) : 0;
  }
  short8 z = {0, 0, 0, 0, 0, 0, 0, 0};
  *(short8*)(buf + ((size_t)s * HP * WP + y * WP + x) * 8) = z;
}

// conv1 PIPELINED: fp32 planar img -> bf16 LDS tile [2][9][130][4] -> MFMA.
// Block = 8 row-groups x 64 px (grid 2 x 4 x C = 1024 blocks, 4/CU).
// 2-deep prefetch: issue loads(t+2); compute(t); convert(t+1); barrier.
// Output h1p layout [c8=4][130][130][8]. Row-group g: out rows 4g..4g+3,
// input rows 8g-1 .. 8g+7.
__global__ __launch_bounds__(256, 4) void conv1p_k(
    const float* __restrict__ img, const unsigned short* __restrict__ wp,
    const float* __restrict__ bias, const int* __restrict__ rgn,
    unsigned short* __restrict__ outp, int b0) {
  __shared__ unsigned short tile[2][9 * 130 * 4];  // 2 x 9,360 B
  __shared__ float sBias[32];
  const int tid = threadIdx.x;
  const int bl = blockIdx.z;
  const int r = __builtin_amdgcn_readfirstlane(rgn[b0 + bl]);
  if (tid < 32) sBias[tid] = bias[r * 32 + tid];
  const int ox0 = blockIdx.x * 64;
  const int g0 = blockIdx.y * 8;  // row-group base (0,8,16,24)
  const float* ib = img + (size_t)(b0 + bl) * 3 * 65536;

  // static interior chunk: thread -> (tr0, xq0), rows 0..7 of the 9-row tile
  const int tr0 = tid >> 5, xq0 = tid & 31;
  const float* p0base = ib + 2 * ox0 + 4 * xq0;

  // weight fragments (hoisted, loop-invariant)
  const int n = tid & 15, q = (tid >> 4) & 3, w = tid >> 6;
  const int lane = tid & 63;
  const short8* wpb = (const short8*)wp + (size_t)r * 256 + lane;
  short8 afr[2][2];
#pragma unroll
  for (int kg = 0; kg < 2; ++kg)
#pragma unroll
    for (int m = 0; m < 2; ++m) afr[kg][m] = wpb[(kg * 2 + m) * 64];

  struct Slot { float4v a, b, c; };
  Slot sA, sB;

  // issue the bulk interior loads for row-group g into slot s
  auto LOADI = [&](int g, Slot& s) {
    int ur = 8 * g + tr0 - 1;  // <= 254 always; < 0 only for g==0, tr0==0
    if (ur >= 0) {
      const float* p = p0base + (size_t)ur * 256;
      s.a = *(const float4v*)p;
      s.b = *(const float4v*)(p + 65536);
      s.c = *(const float4v*)(p + 131072);
    }
  };

  // convert slot + inline tail (row 8 chunk, x-strip halo) into LDS buffer
  auto CONV = [&](int g, Slot& s, unsigned short* tb) {
    // x-strip halo (tile x = 0 / 129), 18 threads, inline scalar loads
    if (tid < 18) {
      int trh = tid >> 1, side = tid & 1;
      int urh = 8 * g + trh - 1;
      int uc = 2 * ox0 + (side ? 128 : -1);
      ushort4v v = {0, 0, 0, 0};
      if (urh >= 0 && (unsigned)uc < 256u) {
        const float* p = ib + (size_t)urh * 256 + uc;
        v.x = f2bf(p[0]);
        v.y = f2bf(p[65536]);
        v.z = f2bf(p[131072]);
      }
      *(ushort4v*)&tb[(size_t)(trh * 130 + (side ? 129 : 0)) * 4] = v;
    }
    // row-8 chunk (always a valid row: ur = 8g+7 <= 255), 32 threads inline
    if (tid < 32) {
      const float* p = ib + (size_t)(8 * g + 7) * 256 + 2 * ox0 + 4 * tid;
      float4v a = *(const float4v*)p;
      float4v bb = *(const float4v*)(p + 65536);
      float4v cc = *(const float4v*)(p + 131072);
      unsigned short* dp = &tb[(size_t)(8 * 130 + 1 + 4 * tid) * 4];
#pragma unroll
      for (int i = 0; i < 4; ++i) {
        ushort4v v = {f2bf(a[i]), f2bf(bb[i]), f2bf(cc[i]), 0};
        *(ushort4v*)(dp + i * 4) = v;
      }
    }
    // bulk interior from prefetched slot
    {
      int ur = 8 * g + tr0 - 1;
      unsigned short* dp = &tb[(size_t)(tr0 * 130 + 1 + 4 * xq0) * 4];
      if (ur >= 0) {
#pragma unroll
        for (int i = 0; i < 4; ++i) {
          ushort4v v = {f2bf(s.a[i]), f2bf(s.b[i]), f2bf(s.c[i]), 0};
          *(ushort4v*)(dp + i * 4) = v;
        }
      } else {
        ushort4v z = {0, 0, 0, 0};
#pragma unroll
        for (int i = 0; i < 4; ++i) *(ushort4v*)(dp + i * 4) = z;
      }
    }
  };

  unsigned short* ob = outp + (size_t)bl * 4 * 130 * 130 * 8;

  // MFMA + bias/ReLU/store for row-group g from LDS buffer tb
  auto COMPUTE = [&](int g, const unsigned short* tb) {
    floatx4 acc[4][2];
#pragma unroll
    for (int nt = 0; nt < 4; ++nt)
#pragma unroll
      for (int m = 0; m < 2; ++m) acc[nt][m] = (floatx4){0.f, 0.f, 0.f, 0.f};
#pragma unroll
    for (int kg = 0; kg < 2; ++kg) {
      int row = kg * 2 + (q >> 1);
      int rowc = (row < 3) ? row : 0;  // pad row: zero weights, safe addr
      int tr = 2 * w + rowc;           // 0..8
#pragma unroll
      for (int nt = 0; nt < 4; ++nt) {
        int lx = nt * 16 + n;  // local out px 0..63
        short8 bfr =
            *(const short8*)&tb[((size_t)tr * 130 + 2 * lx) * 4 + (q & 1) * 8];
#pragma unroll
        for (int m = 0; m < 2; ++m)
          acc[nt][m] = __builtin_amdgcn_mfma_f32_16x16x32_bf16(afr[kg][m], bfr,
                                                               acc[nt][m], 0, 0, 0);
      }
    }
    const int oy = g * 4 + w;
#pragma unroll
    for (int nt = 0; nt < 4; ++nt) {
      int ox = ox0 + nt * 16 + n;
#pragma unroll
      for (int m = 0; m < 2; ++m) {
        ushort4v st;
#pragma unroll
        for (int rr = 0; rr < 4; ++rr) {
          float v = acc[nt][m][rr] + sBias[m * 16 + q * 4 + rr];
          st[rr] = f2bf(v > 0.f ? v : 0.f);
        }
        int cg = m * 2 + (q >> 1);  // oc/8
        *(ushort4v*)(ob + (((size_t)cg * 130 + oy + 1) * 130 + ox + 1) * 8 +
                     (q & 1) * 4) = st;
      }
    }
  };

  // --- pipeline: depth-2 prefetch, double-buffered LDS ---
  LOADI(g0 + 0, sA);
  LOADI(g0 + 1, sB);
  CONV(g0 + 0, sA, tile[0]);
  __syncthreads();

  auto STEP = [&](int t, Slot& ld, Slot& cv, unsigned short* cbuf,
                  unsigned short* nbuf) {
    if (t + 2 < 8) LOADI(g0 + t + 2, ld);   // issue early
    COMPUTE(g0 + t, cbuf);                  // long phase hides the loads
    if (t + 1 < 8) CONV(g0 + t + 1, cv, nbuf);  // regs issued 1 iter ago
    __syncthreads();
  };
  for (int t = 0; t < 8; t += 2) {
    STEP(t, sA, sB, tile[0], tile[1]);
    STEP(t + 1, sB, sA, tile[1], tile[0]);
  }
}

// conv2: 32->64, 64x64 out. Block = 4 out rows x 64 px. h1p [c8=4][130][130][8].
// LDS tile [row][c8][x][8] = chunk c*16B; global chunk run contiguous in x.
__global__ __launch_bounds__(256, 2) void conv2lds_k(
    const unsigned short* __restrict__ in, const unsigned short* __restrict__ wp,
    const float* __restrict__ bias, const int* __restrict__ rgn,
    unsigned short* __restrict__ outp, int b0) {
  __shared__ unsigned short tile[9 * 4 * 130 * 8];  // 74,880 B
  __shared__ float sBias[64];
  const int tid = threadIdx.x;
  const int bl = blockIdx.y;
  const int r = __builtin_amdgcn_readfirstlane(rgn[b0 + bl]);
  if (tid < 64) sBias[tid] = bias[r * 64 + tid];
  const int oy0 = blockIdx.x * 4;
  const int wv = tid >> 6;
  const unsigned short* gsrc = in + (size_t)bl * 4 * 130 * 130 * 8;
  for (int seg = 0; seg < 4680; seg += 256) {
    int c = seg + tid;
    if (c < 4680) {
      int row = c / 520;
      int rem = c - row * 520;
      int c8 = rem / 130;
      int x = rem - c8 * 130;
      const unsigned short* gp =
          gsrc + (((size_t)c8 * 130 + 2 * oy0 + row) * 130 + x) * 8;
      g2l16(gp, tile + (size_t)(seg + wv * 64) * 8);
    }
  }
  __syncthreads();
  const int n = tid & 15, q = (tid >> 4) & 3, w = tid >> 6;
  const short8* wpb = (const short8*)wp + (size_t)r * 9 * 4 * 64 + (tid & 63);
  floatx4 acc[4][4];
#pragma unroll
  for (int nt = 0; nt < 4; ++nt)
#pragma unroll
    for (int m = 0; m < 4; ++m) acc[nt][m] = (floatx4){0.f, 0.f, 0.f, 0.f};
#pragma unroll
  for (int tap = 0; tap < 9; ++tap) {
    const int ky = tap / 3, kx = tap % 3;
    short8 afr[4];
#pragma unroll
    for (int m = 0; m < 4; ++m) afr[m] = wpb[(tap * 4 + m) * 64];
    short8 bfr[4];
#pragma unroll
    for (int nt = 0; nt < 4; ++nt) {
      int ox = nt * 16 + n;
      bfr[nt] = *(const short8*)&tile[((((2 * w + ky) << 2) + q) * 130 +
                                      (2 * ox + kx)) * 8];
    }
#pragma unroll
    for (int m = 0; m < 4; ++m)
#pragma unroll
      for (int nt = 0; nt < 4; ++nt)
        acc[nt][m] = __builtin_amdgcn_mfma_f32_16x16x32_bf16(afr[m], bfr[nt],
                                                             acc[nt][m], 0, 0, 0);
  }
  unsigned short* ob = outp + (size_t)bl * 8 * 66 * 66 * 8;
  const int oy = oy0 + w;
#pragma unroll
  for (int nt = 0; nt < 4; ++nt) {
    int ox = nt * 16 + n;
#pragma unroll
    for (int m = 0; m < 4; ++m) {
      ushort4v st;
#pragma unroll
      for (int rr = 0; rr < 4; ++rr) {
        float v = acc[nt][m][rr] + sBias[m * 16 + q * 4 + rr];
        st[rr] = f2bf(v > 0.f ? v : 0.f);
      }
      int cg = m * 2 + (q >> 1);  // oc/8
      *(ushort4v*)(ob + (((size_t)cg * 66 + oy + 1) * 66 + ox + 1) * 8 +
                   (q & 1) * 4) = st;
    }
  }
}

// conv3: 64->128, 32x32 out, fused bias+ReLU+GAP. h2p [c8=8][66][66][8].
// Block = 128 thr (2 waves), 4 out rows x 32 px, all 128 oc (acc 128 AGPR).
// Two 32-ch K-phases; tile [iy][c8][x][8] = 38,016 B; chunks contiguous in x.
__global__ __launch_bounds__(128, 2) void conv3lds_k(
    const unsigned short* __restrict__ in, const unsigned short* __restrict__ wp,
    const float* __restrict__ bias, const int* __restrict__ rgn,
    float* __restrict__ feat, int b0) {
  __shared__ unsigned short tile[9 * 4 * 66 * 8];  // 38,016 B
  __shared__ float sBias[128];
  __shared__ float sGap[2 * 128];
  const int tid = threadIdx.x;
  const int bl = blockIdx.y;
  const int b = b0 + bl;
  const int r = __builtin_amdgcn_readfirstlane(rgn[b]);
  sBias[tid] = bias[r * 128 + tid];
  const int oy0 = blockIdx.x * 4;
  const unsigned short* gbase = in + (size_t)bl * 8 * 66 * 66 * 8;
  const int lane = tid & 63, wv = tid >> 6;
  const int n = lane & 15, q = (lane >> 4) & 3;
  const short8* wpb = (const short8*)wp + (size_t)r * 9 * 2 * 8 * 64 + lane;
  floatx4 acc[4][8];
#pragma unroll
  for (int nt = 0; nt < 4; ++nt)
#pragma unroll
    for (int m = 0; m < 8; ++m) acc[nt][m] = (floatx4){0.f, 0.f, 0.f, 0.f};
#pragma unroll
  for (int s = 0; s < 2; ++s) {
    __syncthreads();  // previous phase's reads done before restage
    for (int seg = 0; seg < 2376; seg += 128) {
      int c = seg + tid;
      if (c < 2376) {
        int iy = c / 264;
        int rem = c - iy * 264;
        int c8 = rem / 66;
        int x = rem - c8 * 66;
        const unsigned short* gp =
            gbase + (((size_t)(s * 4 + c8) * 66 + 2 * oy0 + iy) * 66 + x) * 8;
        g2l16(gp, tile + (size_t)(seg + wv * 64) * 8);
      }
    }
    __syncthreads();
#pragma unroll
    for (int tap = 0; tap < 9; ++tap) {
      const int ky = tap / 3, kx = tap % 3;
      short8 afr[8];
#pragma unroll
      for (int m = 0; m < 8; ++m) afr[m] = wpb[((tap * 2 + s) * 8 + m) * 64];
      short8 bfr[4];
#pragma unroll
      for (int nt = 0; nt < 4; ++nt) {
        int oyl = 2 * wv + (nt >> 1);          // local out row 0..3
        int ox = ((nt & 1) << 4) + n;          // 0..31
        bfr[nt] = *(const short8*)&tile[(((2 * oyl + ky) * 4 + q) * 66 +
                                        (2 * ox + kx)) * 8];
      }
#pragma unroll
      for (int m = 0; m < 8; ++m)
#pragma unroll
        for (int nt = 0; nt < 4; ++nt)
          acc[nt][m] = __builtin_amdgcn_mfma_f32_16x16x32_bf16(afr[m], bfr[nt],
                                                               acc[nt][m], 0, 0, 0);
    }
  }
  // bias + ReLU + GAP: per-wave shfl reduce, LDS cross-wave combine
#pragma unroll
  for (int m = 0; m < 8; ++m)
#pragma unroll
    for (int rr = 0; rr < 4; ++rr) {
      float bv = sBias[m * 16 + q * 4 + rr];
      float vs = 0.f;
#pragma unroll
      for (int nt = 0; nt < 4; ++nt) {
        float v = acc[nt][m][rr] + bv;
        vs += (v > 0.f ? v : 0.f);
      }
      vs += __shfl_xor(vs, 1, 16);
      vs += __shfl_xor(vs, 2, 16);
      vs += __shfl_xor(vs, 4, 16);
      vs += __shfl_xor(vs, 8, 16);
      if (n == 0) sGap[wv * 128 + m * 16 + q * 4 + rr] = vs;
    }
  __syncthreads();
  atomicAdd(&feat[b * 128 + tid], sGap[tid] + sGap[128 + tid]);
}

__global__ __launch_bounds__(256) void head_k(
    const float* __restrict__ feat, const float* __restrict__ fw,
    const float* __restrict__ fb, const int* __restrict__ rgn,
    float* __restrict__ out) {
  int t = threadIdx.x;  // 128 samples x 2 classes
  int b = t >> 1, c = t & 1;
  int r = rgn[b];
  const float* fwr = fw + (r * 2 + c) * 128;
  const float* fv = feat + b * 128;
  float a = 0.f;
#pragma unroll 8
  for (int j = 0; j < 128; ++j) a = fmaf(fwr[j], fv[j], a);
  out[t] = a * (1.0f / 1024.0f) + fb[r * 2 + c];
}

extern "C" void kernel_launch(void* const* d_in, const int* in_sizes, int n_in,
                              void* d_out, int out_size, void* d_ws, size_t ws_size,
                              hipStream_t stream) {
  const float* img = (const float*)d_in[0];
  const int* rgn_raw = (const int*)d_in[1];
  const float* w1 = (const float*)d_in[2];
  const float* b1 = (const float*)d_in[3];
  const float* w2 = (const float*)d_in[4];
  const float* b2 = (const float*)d_in[5];
  const float* w3 = (const float*)d_in[6];
  const float* b3 = (const float*)d_in[7];
  const float* fw = (const float*)d_in[8];
  const float* fb = (const float*)d_in[9];
  float* out = (float*)d_out;

  const size_t h1p_s = (size_t)4 * 130 * 130 * 8 * 2;  // 1.08 MB
  const size_t h2p_s = (size_t)8 * 66 * 66 * 8 * 2;    // 557 KB
  const size_t per_sample = h1p_s + h2p_s;             // ~1.64 MB
  const size_t fixed = (size_t)16384 * 2 + (size_t)147456 * 2 +
                       (size_t)589824 * 2 + 128 * 128 * 4 + 512 + 16 * 256;
  int C = 128;
  while (C > 1 && fixed + (size_t)C * per_sample > ws_size) C >>= 1;

  char* ws = (char*)d_ws;
  size_t off = 0;
  auto alloc = [&](size_t bytes) {
    char* p = ws + off;
    off += (bytes + 255) & ~(size_t)255;
    return p;
  };
  unsigned short* h1p = (unsigned short*)alloc((size_t)C * h1p_s);
  unsigned short* h2p = (unsigned short*)alloc((size_t)C * h2p_s);
  unsigned short* w1p = (unsigned short*)alloc((size_t)16384 * 2);
  unsigned short* w2p = (unsigned short*)alloc((size_t)147456 * 2);
  unsigned short* w3p = (unsigned short*)alloc((size_t)589824 * 2);
  float* feat = (float*)alloc((size_t)128 * 128 * 4);
  int* rgn = (int*)alloc((size_t)128 * 4);

  hipLaunchKernelGGL(prep_k, dim3(1), dim3(128), 0, stream, rgn_raw, rgn, feat);
  hipLaunchKernelGGL(pack1_k, dim3(64), dim3(256), 0, stream, w1, w1p);
  hipLaunchKernelGGL((packT_k<64, 32, 1, 4>), dim3(576), dim3(256), 0, stream, w2, w2p);
  hipLaunchKernelGGL((packT_k<128, 64, 2, 8>), dim3(2304), dim3(256), 0, stream, w3, w3p);
  {  // zero halos (interiors rewritten every chunk)
    int n1 = C * 4 * (2 * 130 + 2 * 128);
    hipLaunchKernelGGL(halo8_k, dim3((n1 + 255) / 256), dim3(256), 0, stream,
                       h1p, C * 4, 130, 130);
    int n2 = C * 8 * (2 * 66 + 2 * 64);
    hipLaunchKernelGGL(halo8_k, dim3((n2 + 255) / 256), dim3(256), 0, stream,
                       h2p, C * 8, 66, 66);
  }

  for (int b0 = 0; b0 < 128; b0 += C) {
    // conv1 pipelined: grid (x-half, rg-quad, sample) = (2, 4, C)
    hipLaunchKernelGGL(conv1p_k, dim3(2, 4, C), dim3(256), 0, stream,
                       img, w1p, b1, rgn, h1p, b0);
    // conv2: 16 row-group blocks (4 rows x 64 px each) per sample
    hipLaunchKernelGGL(conv2lds_k, dim3(16, C), dim3(256), 0, stream,
                       h1p, w2p, b2, rgn, h2p, b0);
    // conv3: 8 row-group blocks (4 rows x 32 px each) per sample, 128 thr
    hipLaunchKernelGGL(conv3lds_k, dim3(8, C), dim3(128), 0, stream,
                       h2p, w3p, b3, rgn, feat, b0);
  }
  hipLaunchKernelGGL(head_k, dim3(1), dim3(256), 0, stream, feat, fw, fb, rgn, out);
}

// Round 4
// 301.938 us; speedup vs baseline: 1.1687x; 1.1687x over previous
//
#include <hip/hip_runtime.h>
#include <cstdint>

// ---------------------------------------------------------------------------
// RegionModel R18: conv1+conv2 FUSED (h1p eliminated); conv3 = R14.
// R15-R17 established: not HBM-bound (fill=6.9TB/s vs convs 2.5), not
// wave-count-bound (R16 regressed), not source-pipelinable (R17 regressed;
// compiler drains vmcnt at barriers). Every stage is latency-bound at
// 2.5-4x its roofline. So: remove traffic + kernels structurally.
// conv12_k: per block (conv2 out 4 rows x 32 px, xh half):
//   stage img tile [19 rows][168 px][3ch] fp32->bf16 (25.5KB)
//   conv1-MFMA -> h1 LDS tile [9][c8=4][66][8] (38KB, conv2's exact layout)
//   barrier; conv2-MFMA (R16-verified formulas) -> h2p global.
// Eliminates h1p's 135MB write + 135MB read and one serialized dispatch.
// ---------------------------------------------------------------------------

typedef __attribute__((ext_vector_type(8))) short short8;
typedef __attribute__((ext_vector_type(4))) float floatx4;
typedef __attribute__((ext_vector_type(4))) unsigned short ushort4v;
typedef __attribute__((ext_vector_type(4))) float float4v;

__device__ inline unsigned short f2bf(float f) {
  union { float f; unsigned u; } x;
  x.f = f;
  unsigned u = x.u;
  u += 0x7FFFu + ((u >> 16) & 1u);  // round-to-nearest-even
  return (unsigned short)(u >> 16);
}

// Async 16B global->LDS DMA. LDS dest = wave-uniform base + lane*16.
__device__ inline void g2l16(const unsigned short* g, unsigned short* l) {
  __builtin_amdgcn_global_load_lds(
      (const __attribute__((address_space(1))) unsigned int*)g,
      (__attribute__((address_space(3))) unsigned int*)(unsigned int)(uintptr_t)l,
      16, 0, 0);
}

__global__ __launch_bounds__(128) void prep_k(const int* __restrict__ rp,
                                              int* __restrict__ rout,
                                              float* __restrict__ feat) {
  __shared__ int is64;
  if (threadIdx.x == 0) {
    int odd_or = 0;
    for (int i = 0; i < 64; ++i) odd_or |= rp[2 * i + 1];
    is64 = (odd_or == 0) ? 1 : 0;
  }
  __syncthreads();
  int b = threadIdx.x;
  int r = is64 ? rp[2 * b] : rp[b];
  rout[b] = r & 7;
  float* fr = feat + b * 128;
  for (int j = 0; j < 128; ++j) fr[j] = 0.f;
}

// conv1 weights -> [r][kg(2)][mt(2)][lane][j] ; k = kg*32+q*8+j maps to
// row = kg*2+(q>>1), idx=(q&1)*8+j, kx=idx>>2, c=idx&3; pad slots -> 0.
__global__ __launch_bounds__(256) void pack1_k(const float* __restrict__ w,
                                               unsigned short* __restrict__ dst) {
  int t = blockIdx.x * blockDim.x + threadIdx.x;
  if (t >= 16384) return;
  int j = t & 7, lane = (t >> 3) & 63, mt = (t >> 9) & 1, kg = (t >> 10) & 1,
      r = t >> 11;
  int oc = mt * 16 + (lane & 15);
  int q = (lane >> 4) & 3;
  int row = kg * 2 + (q >> 1);
  int idx = (q & 1) * 8 + j;
  int kx = idx >> 2, c = idx & 3;
  float val = 0.f;
  if (row < 3 && kx < 3 && c < 3) val = w[((r * 32 + oc) * 3 + c) * 9 + row * 3 + kx];
  dst[t] = f2bf(val);
}

// conv2/3 weights [R][OC][IC][3][3] -> [r][tap][s][mt][lane][j], ic=s*32+q*8+j
template <int OC, int IC, int SUBK, int MTG>
__global__ __launch_bounds__(256) void packT_k(const float* __restrict__ w,
                                               unsigned short* __restrict__ dst) {
  const int total = 8 * 9 * SUBK * MTG * 512;
  int t = blockIdx.x * blockDim.x + threadIdx.x;
  if (t >= total) return;
  int j = t & 7, lane = (t >> 3) & 63;
  int u = t >> 9;
  int mt = u % MTG; u /= MTG;
  int s = u % SUBK; u /= SUBK;
  int tap = u % 9;
  int r = u / 9;
  int oc = mt * 16 + (lane & 15);
  int ic = s * 32 + ((lane >> 4) & 3) * 8 + j;
  dst[t] = f2bf(w[((r * OC + oc) * IC + ic) * 9 + tap]);
}

// zero halo of channel-group plane buffer [nplane][HP][WP][8]
__global__ __launch_bounds__(256) void halo8_k(unsigned short* __restrict__ buf,
                                               int nplane, int HP, int WP) {
  int per = 2 * WP + 2 * (HP - 2);
  int t = blockIdx.x * blockDim.x + threadIdx.x;
  if (t >= nplane * per) return;
  int s = t / per, i = t - s * per;
  int y, x;
  if (i < WP) { y = 0; x = i; }
  else if (i < 2 * WP) { y = HP - 1; x = i - WP; }
  else {
    int ii = i - 2 * WP;
    y = 1 + (ii >> 1);
    x = (ii & 1) ? (WP - 1) : 0;
  }
  short8 z = {0, 0, 0, 0, 0, 0, 0, 0};
  *(short8*)(buf + ((size_t)s * HP * WP + y * WP + x) * 8) = z;
}

// FUSED conv1+conv2. Block = conv2 out 4 rows x 32 px (xh half of 64).
// Grid (xh 2, yg 16, sample C). Threads 256 (4 waves; wave = 1 out row).
//
// h1 tile semantics: local hy 0..8 <-> real h1 row 2*oy0-1+hy;
//                    local lx 0..65 <-> real h1 px  xh*64-1+lx.
// img tile: row t 0..18 <-> real img row 4*oy0-3+t;
//           col tc 0..167 <-> real img col (xh*128-3)+tc  (odd base so the
//           conv1 b-frag for out px lx starts at EVEN tile col 2*lx).
__global__ __launch_bounds__(256, 2) void conv12_k(
    const float* __restrict__ img, const unsigned short* __restrict__ w1p,
    const float* __restrict__ b1, const unsigned short* __restrict__ w2p,
    const float* __restrict__ b2, const int* __restrict__ rgn,
    unsigned short* __restrict__ outp, int b0) {
  __shared__ unsigned short imgT[19 * 168 * 4];  // 25,536 B
  __shared__ unsigned short h1T[9 * 4 * 66 * 8]; // 38,016 B
  __shared__ float sB1[32];
  __shared__ float sB2[64];
  const int tid = threadIdx.x;
  const int xh = blockIdx.x;        // 0..1
  const int oy0 = blockIdx.y * 4;   // conv2 out row base 0..60
  const int bl = blockIdx.z;
  const int r = __builtin_amdgcn_readfirstlane(rgn[b0 + bl]);
  if (tid < 32) sB1[tid] = b1[r * 32 + tid];
  if (tid >= 64 && tid < 128) sB2[tid - 64] = b2[r * 64 + (tid - 64)];
  const float* ib = img + (size_t)(b0 + bl) * 3 * 65536;
  const int padx = xh ? 65 : 0;          // h1 zero-pad column in this tile
  const bool skiptop = (oy0 == 0);       // hy==0 is real h1 row -1

  // ---- stage img tile (fp32 -> bf16), chunk = 4 px; real col of chunk i=0
  // is rb+4*cq with rb = xh*128-4 (16B-aligned float4 when in range).
  // tile col of chunk element i is 4*cq + i - 1 (skip i=0 when cq==0).
  const int rb = xh * 128 - 4;
  for (int seg = 0; seg < 779; seg += 256) {  // 19 rows * 41 chunks
    int c = seg + tid;
    if (c < 779) {
      int row = c / 41, cq = c - row * 41;
      int rv = 4 * oy0 - 3 + row;            // real img row (never > 255)
      int cb = rb + 4 * cq;                  // real img col of i=0
      unsigned short* dp = &imgT[((size_t)row * 168 + (4 * cq - 1)) * 4];
      bool vr = (rv >= 0);
      if (vr && cq > 0 && cb >= 0 && cb + 3 <= 255) {
        const float* p = ib + (size_t)rv * 256 + cb;
        float4v a = *(const float4v*)p;
        float4v bb = *(const float4v*)(p + 65536);
        float4v cc = *(const float4v*)(p + 131072);
#pragma unroll
        for (int i = 0; i < 4; ++i) {
          ushort4v v = {f2bf(a[i]), f2bf(bb[i]), f2bf(cc[i]), 0};
          *(ushort4v*)(dp + i * 4) = v;
        }
      } else {
        for (int i = (cq == 0 ? 1 : 0); i < 4; ++i) {
          int cc2 = cb + i;
          ushort4v v = {0, 0, 0, 0};
          if (vr && cc2 >= 0 && cc2 <= 255) {
            const float* p = ib + (size_t)rv * 256 + cc2;
            v.x = f2bf(p[0]);
            v.y = f2bf(p[65536]);
            v.z = f2bf(p[131072]);
          }
          *(ushort4v*)(dp + i * 4) = v;
        }
      }
    }
  }
  // ---- pre-zero h1 pad cells (conv1 stores exclude them)
  {
    short8 z8 = {0, 0, 0, 0, 0, 0, 0, 0};
    if (tid < 36) {  // pad column, all 9 hy x 4 cg
      int hy = tid / 4, cg = tid % 4;
      *(short8*)&h1T[(((size_t)hy * 4 + cg) * 66 + padx) * 8] = z8;
    }
    if (skiptop) {  // hy==0 row (real h1 row -1)
      for (int c = tid; c < 264; c += 256) {  // 4 cg x 66 x
        int cg = c / 66, x = c - cg * 66;
        *(short8*)&h1T[(((size_t)0 * 4 + cg) * 66 + x) * 8] = z8;
      }
    }
  }

  const int n = tid & 15, q = (tid >> 4) & 3, wv = tid >> 6;
  const int lane = tid & 63;
  // conv1 weight frags (32 oc = 2 m-tiles; K = 2 kg groups)
  const short8* wpb1 = (const short8*)w1p + (size_t)r * 256 + lane;
  short8 afr1[2][2];
#pragma unroll
  for (int kg = 0; kg < 2; ++kg)
#pragma unroll
    for (int m = 0; m < 2; ++m) afr1[kg][m] = wpb1[(kg * 2 + m) * 64];

  __syncthreads();

  // ---- conv1: produce h1 tile rows hy = wv, wv+4, wv+8(<9)
#pragma unroll
  for (int rep = 0; rep < 3; ++rep) {
    int hy = wv + 4 * rep;
    if (hy <= 8) {
      floatx4 a1[5][2];
#pragma unroll
      for (int nt = 0; nt < 5; ++nt)
#pragma unroll
        for (int m = 0; m < 2; ++m) a1[nt][m] = (floatx4){0.f, 0.f, 0.f, 0.f};
#pragma unroll
      for (int kg = 0; kg < 2; ++kg) {
        int row = kg * 2 + (q >> 1);
        int rowc = (row < 3) ? row : 0;  // pad row: zero weights, safe addr
        int tr = 2 * hy + rowc;          // 0..18
#pragma unroll
        for (int nt = 0; nt < 5; ++nt) {
          int lx = nt * 16 + n;          // h1 local px 0..79 (use 0..65)
          short8 bfr = *(const short8*)&imgT[((size_t)tr * 168 + 2 * lx) * 4 +
                                             (q & 1) * 8];
#pragma unroll
          for (int m = 0; m < 2; ++m)
            a1[nt][m] = __builtin_amdgcn_mfma_f32_16x16x32_bf16(
                afr1[kg][m], bfr, a1[nt][m], 0, 0, 0);
        }
      }
      // bias + ReLU + bf16 -> h1 LDS tile [hy][cg][lx][8]
#pragma unroll
      for (int nt = 0; nt < 5; ++nt) {
        int lx = nt * 16 + n;
        bool ok = (lx <= 65) && (lx != padx) && !(skiptop && hy == 0);
        if (ok) {
#pragma unroll
          for (int m = 0; m < 2; ++m) {
            ushort4v st;
#pragma unroll
            for (int rr = 0; rr < 4; ++rr) {
              float v = a1[nt][m][rr] + sB1[m * 16 + q * 4 + rr];
              st[rr] = f2bf(v > 0.f ? v : 0.f);
            }
            int cg = m * 2 + (q >> 1);
            *(ushort4v*)&h1T[(((size_t)hy * 4 + cg) * 66 + lx) * 8 +
                             (q & 1) * 4] = st;
          }
        }
      }
    }
  }
  __syncthreads();

  // ---- conv2 (R16-verified formulas): out 4 rows x 32 px, 64 oc
  const short8* wpb2 = (const short8*)w2p + (size_t)r * 9 * 4 * 64 + lane;
  floatx4 a2[2][4];
#pragma unroll
  for (int nt = 0; nt < 2; ++nt)
#pragma unroll
    for (int m = 0; m < 4; ++m) a2[nt][m] = (floatx4){0.f, 0.f, 0.f, 0.f};
#pragma unroll
  for (int tap = 0; tap < 9; ++tap) {
    const int ky = tap / 3, kx = tap % 3;
    short8 af[4];
#pragma unroll
    for (int m = 0; m < 4; ++m) af[m] = wpb2[(tap * 4 + m) * 64];
    short8 bf[2];
#pragma unroll
    for (int nt = 0; nt < 2; ++nt) {
      int ox = nt * 16 + n;  // local out px 0..31
      bf[nt] = *(const short8*)&h1T[((((2 * wv + ky) << 2) + q) * 66 +
                                    (2 * ox + kx)) * 8];
    }
#pragma unroll
    for (int m = 0; m < 4; ++m)
#pragma unroll
      for (int nt = 0; nt < 2; ++nt)
        a2[nt][m] = __builtin_amdgcn_mfma_f32_16x16x32_bf16(af[m], bf[nt],
                                                            a2[nt][m], 0, 0, 0);
  }
  unsigned short* ob = outp + (size_t)bl * 8 * 66 * 66 * 8;
  const int oy = oy0 + wv;
#pragma unroll
  for (int nt = 0; nt < 2; ++nt) {
    int ox = xh * 32 + nt * 16 + n;
#pragma unroll
    for (int m = 0; m < 4; ++m) {
      ushort4v st;
#pragma unroll
      for (int rr = 0; rr < 4; ++rr) {
        float v = a2[nt][m][rr] + sB2[m * 16 + q * 4 + rr];
        st[rr] = f2bf(v > 0.f ? v : 0.f);
      }
      int cg = m * 2 + (q >> 1);  // oc/8
      *(ushort4v*)&ob[(((size_t)cg * 66 + oy + 1) * 66 + ox + 1) * 8 +
                      (q & 1) * 4] = st;
    }
  }
}

// conv3: 64->128, 32x32 out, fused bias+ReLU+GAP. h2p [c8=8][66][66][8].
// Block = 128 thr (2 waves), 4 out rows x 32 px, all 128 oc (acc 128 AGPR).
// Two 32-ch K-phases; tile [iy][c8][x][8] = 38,016 B; chunks contiguous in x.
__global__ __launch_bounds__(128, 2) void conv3lds_k(
    const unsigned short* __restrict__ in, const unsigned short* __restrict__ wp,
    const float* __restrict__ bias, const int* __restrict__ rgn,
    float* __restrict__ feat, int b0) {
  __shared__ unsigned short tile[9 * 4 * 66 * 8];  // 38,016 B
  __shared__ float sBias[128];
  __shared__ float sGap[2 * 128];
  const int tid = threadIdx.x;
  const int bl = blockIdx.y;
  const int b = b0 + bl;
  const int r = __builtin_amdgcn_readfirstlane(rgn[b]);
  sBias[tid] = bias[r * 128 + tid];
  const int oy0 = blockIdx.x * 4;
  const unsigned short* gbase = in + (size_t)bl * 8 * 66 * 66 * 8;
  const int lane = tid & 63, wv = tid >> 6;
  const int n = lane & 15, q = (lane >> 4) & 3;
  const short8* wpb = (const short8*)wp + (size_t)r * 9 * 2 * 8 * 64 + lane;
  floatx4 acc[4][8];
#pragma unroll
  for (int nt = 0; nt < 4; ++nt)
#pragma unroll
    for (int m = 0; m < 8; ++m) acc[nt][m] = (floatx4){0.f, 0.f, 0.f, 0.f};
#pragma unroll
  for (int s = 0; s < 2; ++s) {
    __syncthreads();  // previous phase's reads done before restage
    for (int seg = 0; seg < 2376; seg += 128) {
      int c = seg + tid;
      if (c < 2376) {
        int iy = c / 264;
        int rem = c - iy * 264;
        int c8 = rem / 66;
        int x = rem - c8 * 66;
        const unsigned short* gp =
            gbase + (((size_t)(s * 4 + c8) * 66 + 2 * oy0 + iy) * 66 + x) * 8;
        g2l16(gp, tile + (size_t)(seg + wv * 64) * 8);
      }
    }
    __syncthreads();
#pragma unroll
    for (int tap = 0; tap < 9; ++tap) {
      const int ky = tap / 3, kx = tap % 3;
      short8 afr[8];
#pragma unroll
      for (int m = 0; m < 8; ++m) afr[m] = wpb[((tap * 2 + s) * 8 + m) * 64];
      short8 bfr[4];
#pragma unroll
      for (int nt = 0; nt < 4; ++nt) {
        int oyl = 2 * wv + (nt >> 1);          // local out row 0..3
        int ox = ((nt & 1) << 4) + n;          // 0..31
        bfr[nt] = *(const short8*)&tile[(((2 * oyl + ky) * 4 + q) * 66 +
                                        (2 * ox + kx)) * 8];
      }
#pragma unroll
      for (int m = 0; m < 8; ++m)
#pragma unroll
        for (int nt = 0; nt < 4; ++nt)
          acc[nt][m] = __builtin_amdgcn_mfma_f32_16x16x32_bf16(afr[m], bfr[nt],
                                                               acc[nt][m], 0, 0, 0);
    }
  }
  // bias + ReLU + GAP: per-wave shfl reduce, LDS cross-wave combine
#pragma unroll
  for (int m = 0; m < 8; ++m)
#pragma unroll
    for (int rr = 0; rr < 4; ++rr) {
      float bv = sBias[m * 16 + q * 4 + rr];
      float vs = 0.f;
#pragma unroll
      for (int nt = 0; nt < 4; ++nt) {
        float v = acc[nt][m][rr] + bv;
        vs += (v > 0.f ? v : 0.f);
      }
      vs += __shfl_xor(vs, 1, 16);
      vs += __shfl_xor(vs, 2, 16);
      vs += __shfl_xor(vs, 4, 16);
      vs += __shfl_xor(vs, 8, 16);
      if (n == 0) sGap[wv * 128 + m * 16 + q * 4 + rr] = vs;
    }
  __syncthreads();
  atomicAdd(&feat[b * 128 + tid], sGap[tid] + sGap[128 + tid]);
}

__global__ __launch_bounds__(256) void head_k(
    const float* __restrict__ feat, const float* __restrict__ fw,
    const float* __restrict__ fb, const int* __restrict__ rgn,
    float* __restrict__ out) {
  int t = threadIdx.x;  // 128 samples x 2 classes
  int b = t >> 1, c = t & 1;
  int r = rgn[b];
  const float* fwr = fw + (r * 2 + c) * 128;
  const float* fv = feat + b * 128;
  float a = 0.f;
#pragma unroll 8
  for (int j = 0; j < 128; ++j) a = fmaf(fwr[j], fv[j], a);
  out[t] = a * (1.0f / 1024.0f) + fb[r * 2 + c];
}

extern "C" void kernel_launch(void* const* d_in, const int* in_sizes, int n_in,
                              void* d_out, int out_size, void* d_ws, size_t ws_size,
                              hipStream_t stream) {
  const float* img = (const float*)d_in[0];
  const int* rgn_raw = (const int*)d_in[1];
  const float* w1 = (const float*)d_in[2];
  const float* b1 = (const float*)d_in[3];
  const float* w2 = (const float*)d_in[4];
  const float* b2 = (const float*)d_in[5];
  const float* w3 = (const float*)d_in[6];
  const float* b3 = (const float*)d_in[7];
  const float* fw = (const float*)d_in[8];
  const float* fb = (const float*)d_in[9];
  float* out = (float*)d_out;

  const size_t h2p_s = (size_t)8 * 66 * 66 * 8 * 2;  // 557 KB
  const size_t per_sample = h2p_s;
  const size_t fixed = (size_t)16384 * 2 + (size_t)147456 * 2 +
                       (size_t)589824 * 2 + 128 * 128 * 4 + 512 + 16 * 256;
  int C = 128;
  while (C > 1 && fixed + (size_t)C * per_sample > ws_size) C >>= 1;

  char* ws = (char*)d_ws;
  size_t off = 0;
  auto alloc = [&](size_t bytes) {
    char* p = ws + off;
    off += (bytes + 255) & ~(size_t)255;
    return p;
  };
  unsigned short* h2p = (unsigned short*)alloc((size_t)C * h2p_s);
  unsigned short* w1p = (unsigned short*)alloc((size_t)16384 * 2);
  unsigned short* w2p = (unsigned short*)alloc((size_t)147456 * 2);
  unsigned short* w3p = (unsigned short*)alloc((size_t)589824 * 2);
  float* feat = (float*)alloc((size_t)128 * 128 * 4);
  int* rgn = (int*)alloc((size_t)128 * 4);

  hipLaunchKernelGGL(prep_k, dim3(1), dim3(128), 0, stream, rgn_raw, rgn, feat);
  hipLaunchKernelGGL(pack1_k, dim3(64), dim3(256), 0, stream, w1, w1p);
  hipLaunchKernelGGL((packT_k<64, 32, 1, 4>), dim3(576), dim3(256), 0, stream, w2, w2p);
  hipLaunchKernelGGL((packT_k<128, 64, 2, 8>), dim3(2304), dim3(256), 0, stream, w3, w3p);
  {  // zero halo of h2p (interiors rewritten every chunk)
    int n2 = C * 8 * (2 * 66 + 2 * 64);
    hipLaunchKernelGGL(halo8_k, dim3((n2 + 255) / 256), dim3(256), 0, stream,
                       h2p, C * 8, 66, 66);
  }

  for (int b0 = 0; b0 < 128; b0 += C) {
    // fused conv1+conv2: grid (x-half, 16 row-groups, sample)
    hipLaunchKernelGGL(conv12_k, dim3(2, 16, C), dim3(256), 0, stream,
                       img, w1p, b1, w2p, b2, rgn, h2p, b0);
    // conv3: 8 row-group blocks (4 rows x 32 px each) per sample, 128 thr
    hipLaunchKernelGGL(conv3lds_k, dim3(8, C), dim3(128), 0, stream,
                       h2p, w3p, b3, rgn, feat, b0);
  }
  hipLaunchKernelGGL(head_k, dim3(1), dim3(256), 0, stream, feat, fw, fb, rgn, out);
}

// Round 7
// 287.065 us; speedup vs baseline: 1.2293x; 1.0518x over previous
//
#include <hip/hip_runtime.h>
#include <cstdint>

// ---------------------------------------------------------------------------
// RegionModel R19b: conv12 at 3 blocks/CU via two-phase img staging.
// (R19/R19a hit "container failed twice" with zero counters; this is the
// same optimization in minimal-diff form vs the known-running R18: inline
// staging loop (no reg-batch lambda), uniform per-wave conv1 row loop.)
// R18: 302us, conv12=136.9us @ 64KB LDS -> 2 blocks/CU, occ 19.7%,
// HBM 1.08TB/s; phase-serialized block lifetime with no co-resident cover.
// R19b: img tile staged in two phases through an 11-row buffer (rows 0..10,
// then rows 11..18 into slots 0..7; row 10 survives in slot 10).
// imgT 25.5 -> 14.8KB, total LDS 53.2KB -> 3 blocks/CU (12 waves).
// conv3/head unchanged (controls).
// ---------------------------------------------------------------------------

typedef __attribute__((ext_vector_type(8))) short short8;
typedef __attribute__((ext_vector_type(4))) float floatx4;
typedef __attribute__((ext_vector_type(4))) unsigned short ushort4v;
typedef __attribute__((ext_vector_type(4))) float float4v;

__device__ inline unsigned short f2bf(float f) {
  union { float f; unsigned u; } x;
  x.f = f;
  unsigned u = x.u;
  u += 0x7FFFu + ((u >> 16) & 1u);  // round-to-nearest-even
  return (unsigned short)(u >> 16);
}

// Async 16B global->LDS DMA. LDS dest = wave-uniform base + lane*16.
__device__ inline void g2l16(const unsigned short* g, unsigned short* l) {
  __builtin_amdgcn_global_load_lds(
      (const __attribute__((address_space(1))) unsigned int*)g,
      (__attribute__((address_space(3))) unsigned int*)(unsigned int)(uintptr_t)l,
      16, 0, 0);
}

__global__ __launch_bounds__(128) void prep_k(const int* __restrict__ rp,
                                              int* __restrict__ rout,
                                              float* __restrict__ feat) {
  __shared__ int is64;
  if (threadIdx.x == 0) {
    int odd_or = 0;
    for (int i = 0; i < 64; ++i) odd_or |= rp[2 * i + 1];
    is64 = (odd_or == 0) ? 1 : 0;
  }
  __syncthreads();
  int b = threadIdx.x;
  int r = is64 ? rp[2 * b] : rp[b];
  rout[b] = r & 7;
  float* fr = feat + b * 128;
  for (int j = 0; j < 128; ++j) fr[j] = 0.f;
}

// conv1 weights -> [r][kg(2)][mt(2)][lane][j] ; k = kg*32+q*8+j maps to
// row = kg*2+(q>>1), idx=(q&1)*8+j, kx=idx>>2, c=idx&3; pad slots -> 0.
__global__ __launch_bounds__(256) void pack1_k(const float* __restrict__ w,
                                               unsigned short* __restrict__ dst) {
  int t = blockIdx.x * blockDim.x + threadIdx.x;
  if (t >= 16384) return;
  int j = t & 7, lane = (t >> 3) & 63, mt = (t >> 9) & 1, kg = (t >> 10) & 1,
      r = t >> 11;
  int oc = mt * 16 + (lane & 15);
  int q = (lane >> 4) & 3;
  int row = kg * 2 + (q >> 1);
  int idx = (q & 1) * 8 + j;
  int kx = idx >> 2, c = idx & 3;
  float val = 0.f;
  if (row < 3 && kx < 3 && c < 3) val = w[((r * 32 + oc) * 3 + c) * 9 + row * 3 + kx];
  dst[t] = f2bf(val);
}

// conv2/3 weights [R][OC][IC][3][3] -> [r][tap][s][mt][lane][j], ic=s*32+q*8+j
template <int OC, int IC, int SUBK, int MTG>
__global__ __launch_bounds__(256) void packT_k(const float* __restrict__ w,
                                               unsigned short* __restrict__ dst) {
  const int total = 8 * 9 * SUBK * MTG * 512;
  int t = blockIdx.x * blockDim.x + threadIdx.x;
  if (t >= total) return;
  int j = t & 7, lane = (t >> 3) & 63;
  int u = t >> 9;
  int mt = u % MTG; u /= MTG;
  int s = u % SUBK; u /= SUBK;
  int tap = u % 9;
  int r = u / 9;
  int oc = mt * 16 + (lane & 15);
  int ic = s * 32 + ((lane >> 4) & 3) * 8 + j;
  dst[t] = f2bf(w[((r * OC + oc) * IC + ic) * 9 + tap]);
}

// zero halo of channel-group plane buffer [nplane][HP][WP][8]
__global__ __launch_bounds__(256) void halo8_k(unsigned short* __restrict__ buf,
                                               int nplane, int HP, int WP) {
  int per = 2 * WP + 2 * (HP - 2);
  int t = blockIdx.x * blockDim.x + threadIdx.x;
  if (t >= nplane * per) return;
  int s = t / per, i = t - s * per;
  int y, x;
  if (i < WP) { y = 0; x = i; }
  else if (i < 2 * WP) { y = HP - 1; x = i - WP; }
  else {
    int ii = i - 2 * WP;
    y = 1 + (ii >> 1);
    x = (ii & 1) ? (WP - 1) : 0;
  }
  short8 z = {0, 0, 0, 0, 0, 0, 0, 0};
  *(short8*)(buf + ((size_t)s * HP * WP + y * WP + x) * 8) = z;
}

// FUSED conv1+conv2, two-phase img staging. Block = conv2 out 4 rows x 32 px.
// Grid (xh 2, yg 16, sample C). Threads 256 (4 waves; wave = 1 out row).
// h1 tile: hy 0..8 <-> real h1 row 2*oy0-1+hy; lx 0..65 <-> real px xh*64-1+lx.
// img tile row t 0..18 <-> real img row 4*oy0-3+t; col tc <-> (xh*128-3)+tc.
// Phase A: stage t=0..10 (slots 0..10), conv1 hy 0..4.
// Phase B: stage t=11..18 (slots 0..7; slot 10 = t=10 survives), conv1 hy 5..8.
__global__ __launch_bounds__(256, 3) void conv12_k(
    const float* __restrict__ img, const unsigned short* __restrict__ w1p,
    const float* __restrict__ b1, const unsigned short* __restrict__ w2p,
    const float* __restrict__ b2, const int* __restrict__ rgn,
    unsigned short* __restrict__ outp, int b0) {
  __shared__ unsigned short imgT[11 * 168 * 4];  // 14,784 B
  __shared__ unsigned short h1T[9 * 4 * 66 * 8]; // 38,016 B
  __shared__ float sB1[32];
  __shared__ float sB2[64];
  const int tid = threadIdx.x;
  const int xh = blockIdx.x;        // 0..1
  const int oy0 = blockIdx.y * 4;   // conv2 out row base 0..60
  const int bl = blockIdx.z;
  const int r = __builtin_amdgcn_readfirstlane(rgn[b0 + bl]);
  if (tid < 32) sB1[tid] = b1[r * 32 + tid];
  if (tid >= 64 && tid < 128) sB2[tid - 64] = b2[r * 64 + (tid - 64)];
  const float* ib = img + (size_t)(b0 + bl) * 3 * 65536;
  const int padx = xh ? 65 : 0;          // h1 zero-pad column in this tile
  const bool skiptop = (oy0 == 0);       // hy==0 is real h1 row -1
  const int rb = xh * 128 - 4;           // real img col of chunk elem 0

  const int n = tid & 15, q = (tid >> 4) & 3, wv = tid >> 6;
  const int lane = tid & 63;
  // conv1 weight frags (32 oc = 2 m-tiles; K = 2 kg groups)
  const short8* wpb1 = (const short8*)w1p + (size_t)r * 256 + lane;
  short8 afr1[2][2];
#pragma unroll
  for (int kg = 0; kg < 2; ++kg)
#pragma unroll
    for (int m = 0; m < 2; ++m) afr1[kg][m] = wpb1[(kg * 2 + m) * 64];

  // ---- inline staging (R18-verified form): rows t0..t0+nrows-1 -> slots 0..
  auto STAGE = [&](int t0, int nrows) {
    const int nch = nrows * 41;
    for (int seg = 0; seg < nch; seg += 256) {
      int c = seg + tid;
      if (c < nch) {
        int i = c / 41, cq = c - i * 41;
        int rv = 4 * oy0 - 3 + t0 + i;     // real img row
        int cb = rb + 4 * cq;              // real img col of chunk elem 0
        unsigned short* dp = &imgT[((size_t)i * 168 + (4 * cq - 1)) * 4];
        if (rv >= 0 && cq > 0 && cb >= 0 && cb + 3 <= 255) {
          const float* p = ib + (size_t)rv * 256 + cb;
          float4v a = *(const float4v*)p;
          float4v bb = *(const float4v*)(p + 65536);
          float4v cc = *(const float4v*)(p + 131072);
#pragma unroll
          for (int e = 0; e < 4; ++e) {
            ushort4v v = {f2bf(a[e]), f2bf(bb[e]), f2bf(cc[e]), 0};
            *(ushort4v*)(dp + e * 4) = v;
          }
        } else {
          for (int e = (cq == 0 ? 1 : 0); e < 4; ++e) {
            int cc2 = cb + e;
            ushort4v v = {0, 0, 0, 0};
            if (rv >= 0 && cc2 >= 0 && cc2 <= 255) {
              const float* p = ib + (size_t)rv * 256 + cc2;
              v.x = f2bf(p[0]);
              v.y = f2bf(p[65536]);
              v.z = f2bf(p[131072]);
            }
            *(ushort4v*)(dp + e * 4) = v;
          }
        }
      }
    }
  };

  // conv1 for one h1 row hy; phaseB remaps tile row tr -> slot (tr-11 if >=11).
  auto CONV1ROW = [&](int hy, int phaseB) {
    floatx4 a1[5][2];
#pragma unroll
    for (int nt = 0; nt < 5; ++nt)
#pragma unroll
      for (int m = 0; m < 2; ++m) a1[nt][m] = (floatx4){0.f, 0.f, 0.f, 0.f};
#pragma unroll
    for (int kg = 0; kg < 2; ++kg) {
      int row = kg * 2 + (q >> 1);
      int rowc = (row < 3) ? row : 0;  // pad row: zero weights, safe addr
      int tr = 2 * hy + rowc;
      int slot = phaseB ? (tr >= 11 ? tr - 11 : tr) : tr;
#pragma unroll
      for (int nt = 0; nt < 5; ++nt) {
        int lx = nt * 16 + n;          // h1 local px 0..79 (use 0..65)
        short8 bfr = *(const short8*)&imgT[((size_t)slot * 168 + 2 * lx) * 4 +
                                           (q & 1) * 8];
#pragma unroll
        for (int m = 0; m < 2; ++m)
          a1[nt][m] = __builtin_amdgcn_mfma_f32_16x16x32_bf16(
              afr1[kg][m], bfr, a1[nt][m], 0, 0, 0);
      }
    }
    // bias + ReLU + bf16 -> h1 LDS tile [hy][cg][lx][8]
#pragma unroll
    for (int nt = 0; nt < 5; ++nt) {
      int lx = nt * 16 + n;
      bool ok = (lx <= 65) && (lx != padx) && !(skiptop && hy == 0);
      if (ok) {
#pragma unroll
        for (int m = 0; m < 2; ++m) {
          ushort4v st;
#pragma unroll
          for (int rr = 0; rr < 4; ++rr) {
            float v = a1[nt][m][rr] + sB1[m * 16 + q * 4 + rr];
            st[rr] = f2bf(v > 0.f ? v : 0.f);
          }
          int cg = m * 2 + (q >> 1);
          *(ushort4v*)&h1T[(((size_t)hy * 4 + cg) * 66 + lx) * 8 +
                           (q & 1) * 4] = st;
        }
      }
    }
  };

  // ---- phase A: stage rows 0..10 + zero h1 pad cells
  STAGE(0, 11);
  {
    short8 z8 = {0, 0, 0, 0, 0, 0, 0, 0};
    if (tid < 36) {  // pad column, all 9 hy x 4 cg
      int hy = tid / 4, cg = tid % 4;
      *(short8*)&h1T[(((size_t)hy * 4 + cg) * 66 + padx) * 8] = z8;
    }
    if (skiptop) {  // hy==0 row (real h1 row -1)
      for (int c = tid; c < 264; c += 256) {  // 4 cg x 66 x
        int cg = c / 66, x = c - cg * 66;
        *(short8*)&h1T[(((size_t)0 * 4 + cg) * 66 + x) * 8] = z8;
      }
    }
  }
  __syncthreads();

  // ---- conv1 A: hy 0..4 (wave wv does hy = wv, wv+4 if <=4)
  for (int hy = wv; hy <= 4; hy += 4) CONV1ROW(hy, 0);
  __syncthreads();  // conv1-A img reads done before restage

  // ---- phase B: stage rows 11..18 into slots 0..7 (slot 10 = row 10 kept)
  STAGE(11, 8);
  __syncthreads();

  // ---- conv1 B: hy 5..8
  CONV1ROW(5 + wv, 1);
  __syncthreads();

  // ---- conv2: out 4 rows x 32 px, 64 oc (R18-verified formulas)
  const short8* wpb2 = (const short8*)w2p + (size_t)r * 9 * 4 * 64 + lane;
  floatx4 a2[2][4];
#pragma unroll
  for (int nt = 0; nt < 2; ++nt)
#pragma unroll
    for (int m = 0; m < 4; ++m) a2[nt][m] = (floatx4){0.f, 0.f, 0.f, 0.f};
#pragma unroll
  for (int tap = 0; tap < 9; ++tap) {
    const int ky = tap / 3, kx = tap % 3;
    short8 af[4];
#pragma unroll
    for (int m = 0; m < 4; ++m) af[m] = wpb2[(tap * 4 + m) * 64];
    short8 bf[2];
#pragma unroll
    for (int nt = 0; nt < 2; ++nt) {
      int ox = nt * 16 + n;  // local out px 0..31
      bf[nt] = *(const short8*)&h1T[((((2 * wv + ky) << 2) + q) * 66 +
                                    (2 * ox + kx)) * 8];
    }
#pragma unroll
    for (int m = 0; m < 4; ++m)
#pragma unroll
      for (int nt = 0; nt < 2; ++nt)
        a2[nt][m] = __builtin_amdgcn_mfma_f32_16x16x32_bf16(af[m], bf[nt],
                                                            a2[nt][m], 0, 0, 0);
  }
  unsigned short* ob = outp + (size_t)bl * 8 * 66 * 66 * 8;
  const int oy = oy0 + wv;
#pragma unroll
  for (int nt = 0; nt < 2; ++nt) {
    int ox = xh * 32 + nt * 16 + n;
#pragma unroll
    for (int m = 0; m < 4; ++m) {
      ushort4v st;
#pragma unroll
      for (int rr = 0; rr < 4; ++rr) {
        float v = a2[nt][m][rr] + sB2[m * 16 + q * 4 + rr];
        st[rr] = f2bf(v > 0.f ? v : 0.f);
      }
      int cg = m * 2 + (q >> 1);  // oc/8
      *(ushort4v*)&ob[(((size_t)cg * 66 + oy + 1) * 66 + ox + 1) * 8 +
                      (q & 1) * 4] = st;
    }
  }
}

// conv3: 64->128, 32x32 out, fused bias+ReLU+GAP. h2p [c8=8][66][66][8].
// Block = 128 thr (2 waves), 4 out rows x 32 px, all 128 oc (acc 128 AGPR).
// Two 32-ch K-phases; tile [iy][c8][x][8] = 38,016 B; chunks contiguous in x.
__global__ __launch_bounds__(128, 2) void conv3lds_k(
    const unsigned short* __restrict__ in, const unsigned short* __restrict__ wp,
    const float* __restrict__ bias, const int* __restrict__ rgn,
    float* __restrict__ feat, int b0) {
  __shared__ unsigned short tile[9 * 4 * 66 * 8];  // 38,016 B
  __shared__ float sBias[128];
  __shared__ float sGap[2 * 128];
  const int tid = threadIdx.x;
  const int bl = blockIdx.y;
  const int b = b0 + bl;
  const int r = __builtin_amdgcn_readfirstlane(rgn[b]);
  sBias[tid] = bias[r * 128 + tid];
  const int oy0 = blockIdx.x * 4;
  const unsigned short* gbase = in + (size_t)bl * 8 * 66 * 66 * 8;
  const int lane = tid & 63, wv = tid >> 6;
  const int n = lane & 15, q = (lane >> 4) & 3;
  const short8* wpb = (const short8*)wp + (size_t)r * 9 * 2 * 8 * 64 + lane;
  floatx4 acc[4][8];
#pragma unroll
  for (int nt = 0; nt < 4; ++nt)
#pragma unroll
    for (int m = 0; m < 8; ++m) acc[nt][m] = (floatx4){0.f, 0.f, 0.f, 0.f};
#pragma unroll
  for (int s = 0; s < 2; ++s) {
    __syncthreads();  // previous phase's reads done before restage
    for (int seg = 0; seg < 2376; seg += 128) {
      int c = seg + tid;
      if (c < 2376) {
        int iy = c / 264;
        int rem = c - iy * 264;
        int c8 = rem / 66;
        int x = rem - c8 * 66;
        const unsigned short* gp =
            gbase + (((size_t)(s * 4 + c8) * 66 + 2 * oy0 + iy) * 66 + x) * 8;
        g2l16(gp, tile + (size_t)(seg + wv * 64) * 8);
      }
    }
    __syncthreads();
#pragma unroll
    for (int tap = 0; tap < 9; ++tap) {
      const int ky = tap / 3, kx = tap % 3;
      short8 afr[8];
#pragma unroll
      for (int m = 0; m < 8; ++m) afr[m] = wpb[((tap * 2 + s) * 8 + m) * 64];
      short8 bfr[4];
#pragma unroll
      for (int nt = 0; nt < 4; ++nt) {
        int oyl = 2 * wv + (nt >> 1);          // local out row 0..3
        int ox = ((nt & 1) << 4) + n;          // 0..31
        bfr[nt] = *(const short8*)&tile[(((2 * oyl + ky) * 4 + q) * 66 +
                                        (2 * ox + kx)) * 8];
      }
#pragma unroll
      for (int m = 0; m < 8; ++m)
#pragma unroll
        for (int nt = 0; nt < 4; ++nt)
          acc[nt][m] = __builtin_amdgcn_mfma_f32_16x16x32_bf16(afr[m], bfr[nt],
                                                               acc[nt][m], 0, 0, 0);
    }
  }
  // bias + ReLU + GAP: per-wave shfl reduce, LDS cross-wave combine
#pragma unroll
  for (int m = 0; m < 8; ++m)
#pragma unroll
    for (int rr = 0; rr < 4; ++rr) {
      float bv = sBias[m * 16 + q * 4 + rr];
      float vs = 0.f;
#pragma unroll
      for (int nt = 0; nt < 4; ++nt) {
        float v = acc[nt][m][rr] + bv;
        vs += (v > 0.f ? v : 0.f);
      }
      vs += __shfl_xor(vs, 1, 16);
      vs += __shfl_xor(vs, 2, 16);
      vs += __shfl_xor(vs, 4, 16);
      vs += __shfl_xor(vs, 8, 16);
      if (n == 0) sGap[wv * 128 + m * 16 + q * 4 + rr] = vs;
    }
  __syncthreads();
  atomicAdd(&feat[b * 128 + tid], sGap[tid] + sGap[128 + tid]);
}

__global__ __launch_bounds__(256) void head_k(
    const float* __restrict__ feat, const float* __restrict__ fw,
    const float* __restrict__ fb, const int* __restrict__ rgn,
    float* __restrict__ out) {
  int t = threadIdx.x;  // 128 samples x 2 classes
  int b = t >> 1, c = t & 1;
  int r = rgn[b];
  const float* fwr = fw + (r * 2 + c) * 128;
  const float* fv = feat + b * 128;
  float a = 0.f;
#pragma unroll 8
  for (int j = 0; j < 128; ++j) a = fmaf(fwr[j], fv[j], a);
  out[t] = a * (1.0f / 1024.0f) + fb[r * 2 + c];
}

extern "C" void kernel_launch(void* const* d_in, const int* in_sizes, int n_in,
                              void* d_out, int out_size, void* d_ws, size_t ws_size,
                              hipStream_t stream) {
  const float* img = (const float*)d_in[0];
  const int* rgn_raw = (const int*)d_in[1];
  const float* w1 = (const float*)d_in[2];
  const float* b1 = (const float*)d_in[3];
  const float* w2 = (const float*)d_in[4];
  const float* b2 = (const float*)d_in[5];
  const float* w3 = (const float*)d_in[6];
  const float* b3 = (const float*)d_in[7];
  const float* fw = (const float*)d_in[8];
  const float* fb = (const float*)d_in[9];
  float* out = (float*)d_out;

  const size_t h2p_s = (size_t)8 * 66 * 66 * 8 * 2;  // 557 KB
  const size_t per_sample = h2p_s;
  const size_t fixed = (size_t)16384 * 2 + (size_t)147456 * 2 +
                       (size_t)589824 * 2 + 128 * 128 * 4 + 512 + 16 * 256;
  int C = 128;
  while (C > 1 && fixed + (size_t)C * per_sample > ws_size) C >>= 1;

  char* ws = (char*)d_ws;
  size_t off = 0;
  auto alloc = [&](size_t bytes) {
    char* p = ws + off;
    off += (bytes + 255) & ~(size_t)255;
    return p;
  };
  unsigned short* h2p = (unsigned short*)alloc((size_t)C * h2p_s);
  unsigned short* w1p = (unsigned short*)alloc((size_t)16384 * 2);
  unsigned short* w2p = (unsigned short*)alloc((size_t)147456 * 2);
  unsigned short* w3p = (unsigned short*)alloc((size_t)589824 * 2);
  float* feat = (float*)alloc((size_t)128 * 128 * 4);
  int* rgn = (int*)alloc((size_t)128 * 4);

  hipLaunchKernelGGL(prep_k, dim3(1), dim3(128), 0, stream, rgn_raw, rgn, feat);
  hipLaunchKernelGGL(pack1_k, dim3(64), dim3(256), 0, stream, w1, w1p);
  hipLaunchKernelGGL((packT_k<64, 32, 1, 4>), dim3(576), dim3(256), 0, stream, w2, w2p);
  hipLaunchKernelGGL((packT_k<128, 64, 2, 8>), dim3(2304), dim3(256), 0, stream, w3, w3p);
  {  // zero halo of h2p (interiors rewritten every chunk)
    int n2 = C * 8 * (2 * 66 + 2 * 64);
    hipLaunchKernelGGL(halo8_k, dim3((n2 + 255) / 256), dim3(256), 0, stream,
                       h2p, C * 8, 66, 66);
  }

  for (int b0 = 0; b0 < 128; b0 += C) {
    // fused conv1+conv2: grid (x-half, 16 row-groups, sample)
    hipLaunchKernelGGL(conv12_k, dim3(2, 16, C), dim3(256), 0, stream,
                       img, w1p, b1, w2p, b2, rgn, h2p, b0);
    // conv3: 8 row-group blocks (4 rows x 32 px each) per sample, 128 thr
    hipLaunchKernelGGL(conv3lds_k, dim3(8, C), dim3(128), 0, stream,
                       h2p, w3p, b3, rgn, feat, b0);
  }
  hipLaunchKernelGGL(head_k, dim3(1), dim3(256), 0, stream, feat, fw, fb, rgn, out);
}